// Round 6
// baseline (182.782 us; speedup 1.0000x reference)
//
#include <hip/hip_runtime.h>
#include <hip/hip_bf16.h>
#include <stdint.h>

typedef __attribute__((ext_vector_type(8))) __bf16 bf16x8;
typedef __attribute__((ext_vector_type(16))) float floatx16;

#if __has_builtin(__builtin_amdgcn_exp2f)
#define EXP2F(x) __builtin_amdgcn_exp2f(x)
#else
#define EXP2F(x) exp2f(x)
#endif

#define GAS __attribute__((address_space(1)))
#define LAS __attribute__((address_space(3)))

// sqrt(2*log2(e)): baked into normalized rows so dot = 2*log2(e)*cos and
// sim = exp2(dot) = exp(cos/0.5) with zero epilogue multiplies.
#define SCALE_SQRT 1.69864359f
#define JCH 32  // j-chunks; grid = 64 strips x 32 chunks = 2048 blocks (~5/CU by LDS)

// ---------------- prep: int64-probe labels + normalize -----------------------
__global__ __launch_bounds__(256) void k_prep(const float* __restrict__ x,
                                              const int* __restrict__ raw,
                                              ushort* __restrict__ xb,
                                              unsigned char* __restrict__ lab8,
                                              int N) {
  const int row = (blockIdx.x * 256 + threadIdx.x) >> 6;  // one wave per row
  const int lane = threadIdx.x & 63;
  if (row >= N) return;
  // parallel int64 detection: odd words all zero => labels are int64
  const int probe = raw[2 * lane + 1];
  const bool is64 = (__ballot(probe != 0) == 0ull);
  const float2 v = ((const float2*)(x + (size_t)row * 128))[lane];
  float ss = v.x * v.x + v.y * v.y;
#pragma unroll
  for (int m = 1; m < 64; m <<= 1) ss += __shfl_xor(ss, m, 64);
  const float rn = SCALE_SQRT / fmaxf(sqrtf(ss), 1e-12f);
  __hip_bfloat162 o;
  o.x = __float2bfloat16(v.x * rn);
  o.y = __float2bfloat16(v.y * rn);
  ((__hip_bfloat162*)xb)[row * 64 + lane] = o;
  // labels are 0..63 -> byte-pack (lossless)
  if (lane == 0) lab8[row] = (unsigned char)(is64 ? raw[2 * row] : raw[row]);
}

// ---------------- main: R1 structure, 4x the blocks --------------------------
// grid (JCH=32, N/128). Block: 256 thr = 4 waves; each wave owns a 32-row band
// of the 128-row strip and ALL 64 cols of each j-tile. jpb = 4 j-tiles/block.
// A fragments from global regs (xb = 2 MB, L2-resident); B LDS-staged via
// global_load_lds (XOR-16 source permute), 2x16 KB double-buffer; one barrier
// per tile. Identical inner loop to the best-measured round (98.1 us); only
// concurrency changed: 2048 blocks -> ~5 resident blocks/CU (LDS-capped)
// instead of the old grid-capped 2.
__global__ __launch_bounds__(256, 4) void k_sim(const ushort* __restrict__ xb,
                                                const unsigned char* __restrict__ lab8,
                                                float2* __restrict__ ppart,
                                                int N, int jpb) {
  __shared__ ushort ldsB[2][64 * 128];  // 2 x 16 KB
  const int tid = threadIdx.x;
  const int lane = tid & 63;
  const int wv = tid >> 6;
  const int l31 = lane & 31, g2 = lane >> 5;
  const int l15 = lane & 15, g4 = lane >> 4;
  const int i0 = blockIdx.y * 128;
  const int c = blockIdx.x;
  const int jt0 = c * jpb;

  // ---- stage first B tile ----
  {
    const int j0 = jt0 * 64;
#pragma unroll
    for (int it = 0; it < 4; ++it) {
      const int r0 = it * 16 + wv * 4;  // wave-uniform LDS row base
      const int lr = r0 + g4;
      const int kb = l15 ^ (lr & 15);
      const ushort* gp = xb + (size_t)(j0 + lr) * 128 + kb * 8;
      __builtin_amdgcn_global_load_lds((GAS void*)gp, (LAS void*)&ldsB[0][r0 * 128], 16, 0, 0);
    }
  }

  // ---- A fragments straight from global (L2-hot): rows wv*32+l31 ----
  const int arow = i0 + wv * 32 + l31;
  bf16x8 af[8];
#pragma unroll
  for (int kt = 0; kt < 8; ++kt)
    af[kt] = *(const bf16x8*)(xb + (size_t)arow * 128 + (kt * 2 + g2) * 8);

  // row labels byte-packed (C=64 < 256): word q holds rows wv*32+8q+4*g2+{0..3}
  // (C/D 32x32 layout: col=lane&31, row=(reg&3)+8*(reg>>2)+4*(lane>>5))
  const uint* lab32 = (const uint*)lab8;
  uint liw[4];
#pragma unroll
  for (int q = 0; q < 4; ++q)
    liw[q] = lab32[(i0 + wv * 32 + 8 * q + 4 * g2) >> 2];

  floatx16 vneg = (floatx16)(0.0f), vpos = (floatx16)(0.0f);
  __syncthreads();  // B0 staged (vmcnt drained per wave at barrier)

  for (int t = 0; t < jpb; ++t) {
    const int j0 = (jt0 + t) * 64;
    const int buf = t & 1;
    if (t + 1 < jpb) {  // prefetch next B into other buffer; lands during compute
      const int jn = j0 + 64;
#pragma unroll
      for (int it = 0; it < 4; ++it) {
        const int r0 = it * 16 + wv * 4;
        const int lr = r0 + g4;
        const int kb = l15 ^ (lr & 15);
        const ushort* gp = xb + (size_t)(jn + lr) * 128 + kb * 8;
        __builtin_amdgcn_global_load_lds((GAS void*)gp, (LAS void*)&ldsB[buf ^ 1][r0 * 128], 16, 0, 0);
      }
    }
    const int lj0 = lab8[j0 + l31];       // column labels, both halves
    const int lj1 = lab8[j0 + 32 + l31];

    floatx16 acc0 = (floatx16)(0.0f), acc1 = (floatx16)(0.0f);
    __builtin_amdgcn_s_setprio(1);
#pragma unroll
    for (int kt = 0; kt < 8; ++kt) {
      const int br0 = l31;
      const int br1 = 32 + l31;
      const bf16x8 b0 = *(const bf16x8*)&ldsB[buf][br0 * 128 + (((kt * 2 + g2) ^ (br0 & 15)) * 8)];
      const bf16x8 b1 = *(const bf16x8*)&ldsB[buf][br1 * 128 + (((kt * 2 + g2) ^ (br1 & 15)) * 8)];
      acc0 = __builtin_amdgcn_mfma_f32_32x32x16_bf16(af[kt], b0, acc0, 0, 0, 0);
      acc1 = __builtin_amdgcn_mfma_f32_32x32x16_bf16(af[kt], b1, acc1, 0, 0, 0);
    }
    __builtin_amdgcn_s_setprio(0);

    // ---- epilogue: exp2, diag-skip, row accumulation (registers only) ----
    const int dlt = j0 - i0;             // tile touches diagonal iff dlt in [0,128)
    const bool diag = ((unsigned)dlt < 128u);
    const int jc0 = l31 + dlt;           // global-diag test (h=0): ir == jc
    const int jc1 = 32 + l31 + dlt;      // h=1
    auto epi = [&](bool DG) {
#pragma unroll
      for (int r = 0; r < 16; ++r) {
        const int lr = (liw[r >> 2] >> ((r & 3) * 8)) & 255;
        float e0 = EXP2F(acc0[r]);
        float e1 = EXP2F(acc1[r]);
        if (DG) {
          const int ir = wv * 32 + (r & 3) + 8 * (r >> 2) + 4 * g2;
          if (ir == jc0) e0 = 0.0f;      // exclude self-similarity exactly
          if (ir == jc1) e1 = 0.0f;
        }
        vneg[r] += e0 + e1;
        vpos[r] += ((lr == lj0) ? e0 : 0.0f) + ((lr == lj1) ? e1 : 0.0f);
      }
    };
    if (diag) epi(true); else epi(false);
    __syncthreads();  // all reads of buf done; prefetch(t+1) already drained
  }

  // ---- flush: reduce over 32 col-lanes; single writer lane per row ----
#pragma unroll
  for (int r = 0; r < 16; ++r) {
    float n = vneg[r], p = vpos[r];
#pragma unroll
    for (int m = 1; m < 32; m <<= 1) {
      n += __shfl_xor(n, m, 64);
      p += __shfl_xor(p, m, 64);
    }
    if (l31 == 0) {
      const int row = i0 + wv * 32 + (r & 3) + 8 * (r >> 2) + 4 * g2;
      ppart[(size_t)c * N + row] = float2{n, p};
    }
  }
}

// ---------------- finalize: parallel over 32 blocks, 1 row/thread ------------
__global__ __launch_bounds__(256) void k_final(const float2* __restrict__ ppart,
                                               const unsigned char* __restrict__ lab8,
                                               double* __restrict__ partial,
                                               int N, int nplanes) {
  __shared__ int h[64];
  __shared__ double wsum[4];
  const int tid = threadIdx.x;
  if (tid < 64) h[tid] = 0;
  __syncthreads();
  for (int i = tid; i < N; i += 256) atomicAdd(&h[lab8[i] & 63], 1);
  __syncthreads();
  const int r = blockIdx.x * 256 + tid;
  double v = 0.0;
  if (r < N) {
    float n = 0.0f, p = 0.0f;
#pragma unroll 8
    for (int cc = 0; cc < nplanes; ++cc) {
      const float2 w = ppart[(size_t)cc * N + r];
      n += w.x;
      p += w.y;
    }
    const float cnt = (float)(h[lab8[r] & 63] - 1);
    v = (double)logf(n * cnt / p);
  }
#pragma unroll
  for (int m = 1; m < 64; m <<= 1) v += __shfl_xor(v, m, 64);
  if ((tid & 63) == 0) wsum[tid >> 6] = v;
  __syncthreads();
  if (tid == 0) partial[blockIdx.x] = wsum[0] + wsum[1] + wsum[2] + wsum[3];
}

__global__ __launch_bounds__(64) void k_write(const double* __restrict__ partial,
                                              float* __restrict__ out, int nfb, int N) {
  const int l = threadIdx.x;
  double v = 0.0;
  for (int i = l; i < nfb; i += 64) v += partial[i];
#pragma unroll
  for (int m = 1; m < 64; m <<= 1) v += __shfl_xor(v, m, 64);
  if (l == 0) out[0] = (float)(v / (double)N);
}

extern "C" void kernel_launch(void* const* d_in, const int* in_sizes, int n_in,
                              void* d_out, int out_size, void* d_ws, size_t ws_size,
                              hipStream_t stream) {
  const float* x = (const float*)d_in[0];
  const int* raw_label = (const int*)d_in[1];
  const int N = in_sizes[1];  // 8192
  char* ws = (char*)d_ws;
  ushort* xb = (ushort*)ws;                             // N*128 bf16 = 2 MB
  float2* ppart = (float2*)(ws + (size_t)N * 128 * 2);  // JCH*N float2 = 2 MB
  unsigned char* lab8 = (unsigned char*)(ppart + (size_t)JCH * N);  // N bytes
  double* partial = (double*)(lab8 + ((N + 7) & ~7));   // <=64 doubles
  float* out = (float*)d_out;

  const int jpb = (N / 64) / JCH;   // 4 j-tiles per block
  const int nfb = (N + 255) / 256;  // 32 finalize blocks

  k_prep<<<dim3(N / 4), dim3(256), 0, stream>>>(x, raw_label, xb, lab8, N);
  k_sim<<<dim3(JCH, N / 128), dim3(256), 0, stream>>>(xb, lab8, ppart, N, jpb);
  k_final<<<dim3(nfb), dim3(256), 0, stream>>>(ppart, lab8, partial, N, JCH);
  k_write<<<dim3(1), dim3(64), 0, stream>>>(partial, out, nfb, N);
}

// Round 7
// 112.402 us; speedup vs baseline: 1.6261x; 1.6261x over previous
//
#include <hip/hip_runtime.h>
#include <hip/hip_bf16.h>
#include <stdint.h>

typedef __attribute__((ext_vector_type(8))) __bf16 bf16x8;
typedef __attribute__((ext_vector_type(16))) float floatx16;

#if __has_builtin(__builtin_amdgcn_exp2f)
#define EXP2F(x) __builtin_amdgcn_exp2f(x)
#else
#define EXP2F(x) exp2f(x)
#endif

#define GAS __attribute__((address_space(1)))
#define LAS __attribute__((address_space(3)))

// sqrt(2*log2(e)): baked into normalized rows so dot = 2*log2(e)*cos and
// sim = exp2(dot) = exp(cos/0.5) with zero epilogue multiplies.
#define SCALE_SQRT 1.69864359f
#define JCH 32  // j-chunks; grid = 64 strips x 32 chunks = 2048 blocks

// ---------------- prep: int64-probe labels + normalize -----------------------
__global__ __launch_bounds__(256) void k_prep(const float* __restrict__ x,
                                              const int* __restrict__ raw,
                                              ushort* __restrict__ xb,
                                              unsigned char* __restrict__ lab8,
                                              int N) {
  const int row = (blockIdx.x * 256 + threadIdx.x) >> 6;  // one wave per row
  const int lane = threadIdx.x & 63;
  if (row >= N) return;
  // parallel int64 detection: odd words all zero => labels are int64
  const int probe = raw[2 * lane + 1];
  const bool is64 = (__ballot(probe != 0) == 0ull);
  const float2 v = ((const float2*)(x + (size_t)row * 128))[lane];
  float ss = v.x * v.x + v.y * v.y;
#pragma unroll
  for (int m = 1; m < 64; m <<= 1) ss += __shfl_xor(ss, m, 64);
  const float rn = SCALE_SQRT / fmaxf(sqrtf(ss), 1e-12f);
  __hip_bfloat162 o;
  o.x = __float2bfloat16(v.x * rn);
  o.y = __float2bfloat16(v.y * rn);
  ((__hip_bfloat162*)xb)[row * 64 + lane] = o;
  // labels are 0..63 -> byte-pack (lossless)
  if (lane == 0) lab8[row] = (unsigned char)(is64 ? raw[2 * row] : raw[row]);
}

// ---------------- main: R1 structure, 4x the blocks, SANE regalloc -----------
// grid (JCH=32, N/128). Block: 256 thr = 4 waves; each wave owns a 32-row band
// of the 128-row strip and ALL 64 cols of each j-tile. jpb = 4 j-tiles/block.
// A fragments in registers (xb = 2 MB, L2-resident); B LDS-staged via
// global_load_lds (XOR-16 source permute), 2x16 KB double-buffer; one barrier
// per tile. R6 lesson: __launch_bounds__(256,4) forced VGPR=64 -> ~50
// regs/thread spilled -> 385 MB/dispatch scratch traffic. (256,2) keeps the
// R1-proven allocation (VGPR ~84, zero spill); residency is then LDS/VGPR-
// bound at ~4-5 blocks/CU vs the old grid-capped 2 -> cross-block interleave
// fills the per-tile barrier bubbles.
__global__ __launch_bounds__(256, 2) void k_sim(const ushort* __restrict__ xb,
                                                const unsigned char* __restrict__ lab8,
                                                float2* __restrict__ ppart,
                                                int N, int jpb) {
  __shared__ ushort ldsB[2][64 * 128];  // 2 x 16 KB
  const int tid = threadIdx.x;
  const int lane = tid & 63;
  const int wv = tid >> 6;
  const int l31 = lane & 31, g2 = lane >> 5;
  const int l15 = lane & 15, g4 = lane >> 4;
  const int i0 = blockIdx.y * 128;
  const int c = blockIdx.x;
  const int jt0 = c * jpb;

  // ---- stage first B tile ----
  {
    const int j0 = jt0 * 64;
#pragma unroll
    for (int it = 0; it < 4; ++it) {
      const int r0 = it * 16 + wv * 4;  // wave-uniform LDS row base
      const int lr = r0 + g4;
      const int kb = l15 ^ (lr & 15);
      const ushort* gp = xb + (size_t)(j0 + lr) * 128 + kb * 8;
      __builtin_amdgcn_global_load_lds((GAS void*)gp, (LAS void*)&ldsB[0][r0 * 128], 16, 0, 0);
    }
  }

  // ---- A fragments straight from global (L2-hot): rows wv*32+l31 ----
  const int arow = i0 + wv * 32 + l31;
  bf16x8 af[8];
#pragma unroll
  for (int kt = 0; kt < 8; ++kt)
    af[kt] = *(const bf16x8*)(xb + (size_t)arow * 128 + (kt * 2 + g2) * 8);

  // row labels byte-packed (C=64 < 256): word q holds rows wv*32+8q+4*g2+{0..3}
  // (C/D 32x32 layout: col=lane&31, row=(reg&3)+8*(reg>>2)+4*(lane>>5))
  const uint* lab32 = (const uint*)lab8;
  uint liw[4];
#pragma unroll
  for (int q = 0; q < 4; ++q)
    liw[q] = lab32[(i0 + wv * 32 + 8 * q + 4 * g2) >> 2];

  floatx16 vneg = (floatx16)(0.0f), vpos = (floatx16)(0.0f);
  __syncthreads();  // B0 staged (vmcnt drained per wave at barrier)

  for (int t = 0; t < jpb; ++t) {
    const int j0 = (jt0 + t) * 64;
    const int buf = t & 1;
    if (t + 1 < jpb) {  // prefetch next B into other buffer; lands during compute
      const int jn = j0 + 64;
#pragma unroll
      for (int it = 0; it < 4; ++it) {
        const int r0 = it * 16 + wv * 4;
        const int lr = r0 + g4;
        const int kb = l15 ^ (lr & 15);
        const ushort* gp = xb + (size_t)(jn + lr) * 128 + kb * 8;
        __builtin_amdgcn_global_load_lds((GAS void*)gp, (LAS void*)&ldsB[buf ^ 1][r0 * 128], 16, 0, 0);
      }
    }
    const int lj0 = lab8[j0 + l31];       // column labels, both halves
    const int lj1 = lab8[j0 + 32 + l31];

    floatx16 acc0 = (floatx16)(0.0f), acc1 = (floatx16)(0.0f);
    __builtin_amdgcn_s_setprio(1);
#pragma unroll
    for (int kt = 0; kt < 8; ++kt) {
      const int br0 = l31;
      const int br1 = 32 + l31;
      const bf16x8 b0 = *(const bf16x8*)&ldsB[buf][br0 * 128 + (((kt * 2 + g2) ^ (br0 & 15)) * 8)];
      const bf16x8 b1 = *(const bf16x8*)&ldsB[buf][br1 * 128 + (((kt * 2 + g2) ^ (br1 & 15)) * 8)];
      acc0 = __builtin_amdgcn_mfma_f32_32x32x16_bf16(af[kt], b0, acc0, 0, 0, 0);
      acc1 = __builtin_amdgcn_mfma_f32_32x32x16_bf16(af[kt], b1, acc1, 0, 0, 0);
    }
    __builtin_amdgcn_s_setprio(0);

    // ---- epilogue: exp2, diag-skip, row accumulation (registers only) ----
    const int dlt = j0 - i0;             // tile touches diagonal iff dlt in [0,128)
    const bool diag = ((unsigned)dlt < 128u);
    const int jc0 = l31 + dlt;           // global-diag test (h=0): ir == jc
    const int jc1 = 32 + l31 + dlt;      // h=1
    auto epi = [&](bool DG) {
#pragma unroll
      for (int r = 0; r < 16; ++r) {
        const int lr = (liw[r >> 2] >> ((r & 3) * 8)) & 255;
        float e0 = EXP2F(acc0[r]);
        float e1 = EXP2F(acc1[r]);
        if (DG) {
          const int ir = wv * 32 + (r & 3) + 8 * (r >> 2) + 4 * g2;
          if (ir == jc0) e0 = 0.0f;      // exclude self-similarity exactly
          if (ir == jc1) e1 = 0.0f;
        }
        vneg[r] += e0 + e1;
        vpos[r] += ((lr == lj0) ? e0 : 0.0f) + ((lr == lj1) ? e1 : 0.0f);
      }
    };
    if (diag) epi(true); else epi(false);
    __syncthreads();  // all reads of buf done; prefetch(t+1) already drained
  }

  // ---- flush: reduce over 32 col-lanes; single writer lane per row ----
#pragma unroll
  for (int r = 0; r < 16; ++r) {
    float n = vneg[r], p = vpos[r];
#pragma unroll
    for (int m = 1; m < 32; m <<= 1) {
      n += __shfl_xor(n, m, 64);
      p += __shfl_xor(p, m, 64);
    }
    if (l31 == 0) {
      const int row = i0 + wv * 32 + (r & 3) + 8 * (r >> 2) + 4 * g2;
      ppart[(size_t)c * N + row] = float2{n, p};
    }
  }
}

// ---------------- finalize: parallel over 32 blocks, 1 row/thread ------------
__global__ __launch_bounds__(256) void k_final(const float2* __restrict__ ppart,
                                               const unsigned char* __restrict__ lab8,
                                               double* __restrict__ partial,
                                               int N, int nplanes) {
  __shared__ int h[64];
  __shared__ double wsum[4];
  const int tid = threadIdx.x;
  if (tid < 64) h[tid] = 0;
  __syncthreads();
  for (int i = tid; i < N; i += 256) atomicAdd(&h[lab8[i] & 63], 1);
  __syncthreads();
  const int r = blockIdx.x * 256 + tid;
  double v = 0.0;
  if (r < N) {
    float n = 0.0f, p = 0.0f;
#pragma unroll 8
    for (int cc = 0; cc < nplanes; ++cc) {
      const float2 w = ppart[(size_t)cc * N + r];
      n += w.x;
      p += w.y;
    }
    const float cnt = (float)(h[lab8[r] & 63] - 1);
    v = (double)logf(n * cnt / p);
  }
#pragma unroll
  for (int m = 1; m < 64; m <<= 1) v += __shfl_xor(v, m, 64);
  if ((tid & 63) == 0) wsum[tid >> 6] = v;
  __syncthreads();
  if (tid == 0) partial[blockIdx.x] = wsum[0] + wsum[1] + wsum[2] + wsum[3];
}

__global__ __launch_bounds__(64) void k_write(const double* __restrict__ partial,
                                              float* __restrict__ out, int nfb, int N) {
  const int l = threadIdx.x;
  double v = 0.0;
  for (int i = l; i < nfb; i += 64) v += partial[i];
#pragma unroll
  for (int m = 1; m < 64; m <<= 1) v += __shfl_xor(v, m, 64);
  if (l == 0) out[0] = (float)(v / (double)N);
}

extern "C" void kernel_launch(void* const* d_in, const int* in_sizes, int n_in,
                              void* d_out, int out_size, void* d_ws, size_t ws_size,
                              hipStream_t stream) {
  const float* x = (const float*)d_in[0];
  const int* raw_label = (const int*)d_in[1];
  const int N = in_sizes[1];  // 8192
  char* ws = (char*)d_ws;
  ushort* xb = (ushort*)ws;                             // N*128 bf16 = 2 MB
  float2* ppart = (float2*)(ws + (size_t)N * 128 * 2);  // JCH*N float2 = 2 MB
  unsigned char* lab8 = (unsigned char*)(ppart + (size_t)JCH * N);  // N bytes
  double* partial = (double*)(lab8 + ((N + 7) & ~7));   // <=64 doubles
  float* out = (float*)d_out;

  const int jpb = (N / 64) / JCH;   // 4 j-tiles per block
  const int nfb = (N + 255) / 256;  // 32 finalize blocks

  k_prep<<<dim3(N / 4), dim3(256), 0, stream>>>(x, raw_label, xb, lab8, N);
  k_sim<<<dim3(JCH, N / 128), dim3(256), 0, stream>>>(xb, lab8, ppart, N, jpb);
  k_final<<<dim3(nfb), dim3(256), 0, stream>>>(ppart, lab8, partial, N, JCH);
  k_write<<<dim3(1), dim3(64), 0, stream>>>(partial, out, nfb, N);
}

// Round 9
// 107.019 us; speedup vs baseline: 1.7079x; 1.0503x over previous
//
#include <hip/hip_runtime.h>
#include <hip/hip_bf16.h>
#include <stdint.h>

typedef __attribute__((ext_vector_type(8))) __bf16 bf16x8;
typedef __attribute__((ext_vector_type(16))) float floatx16;

#if __has_builtin(__builtin_amdgcn_exp2f)
#define EXP2F(x) __builtin_amdgcn_exp2f(x)
#else
#define EXP2F(x) exp2f(x)
#endif

#define GAS __attribute__((address_space(1)))
#define LAS __attribute__((address_space(3)))

// sqrt(2*log2(e)): baked into normalized rows so dot = 2*log2(e)*cos and
// sim = exp2(dot) = exp(cos/0.5) with zero epilogue multiplies.
#define SCALE_SQRT 1.69864359f
#define JCH 16  // j-chunks; grid = 32 strips x 16 chunks = 512 blocks = 2/CU

// ---------------- prep: int64-probe labels + normalize -----------------------
__global__ __launch_bounds__(256) void k_prep(const float* __restrict__ x,
                                              const int* __restrict__ raw,
                                              ushort* __restrict__ xb,
                                              unsigned char* __restrict__ lab8,
                                              int N) {
  const int row = (blockIdx.x * 256 + threadIdx.x) >> 6;  // one wave per row
  const int lane = threadIdx.x & 63;
  if (row >= N) return;
  // parallel int64 detection: odd words all zero => labels are int64
  const int probe = raw[2 * lane + 1];
  const bool is64 = (__ballot(probe != 0) == 0ull);
  const float2 v = ((const float2*)(x + (size_t)row * 128))[lane];
  float ss = v.x * v.x + v.y * v.y;
#pragma unroll
  for (int m = 1; m < 64; m <<= 1) ss += __shfl_xor(ss, m, 64);
  const float rn = SCALE_SQRT / fmaxf(sqrtf(ss), 1e-12f);
  __hip_bfloat162 o;
  o.x = __float2bfloat16(v.x * rn);
  o.y = __float2bfloat16(v.y * rn);
  ((__hip_bfloat162*)xb)[row * 64 + lane] = o;
  // labels are 0..63 -> byte-pack (lossless)
  if (lane == 0) lab8[row] = (unsigned char)(is64 ? raw[2 * row] : raw[row]);
}

// ---------------- main: R1 pipeline, 64 rows per wave ------------------------
// Clock reality (R2 counters): core runs ~680 MHz on these short kernels, so
// the R1 structure was LDS-pipe-bound (~36 us of ds_read_b128/CU). Fix: each
// wave owns 64 rows x 64 cols (strip = 256 rows, 4 waves), so every B
// ds_read_b128 feeds TWO MFMAs (rh=0,1) -> LDS bytes/element halve (~18 us),
// dropping below the epilogue VALU floor (~24 us). A fragments af[2][8] in
// registers from L2-resident xb; acc serialized per col-half (32 live regs);
// B double-buffered in LDS via global_load_lds + XOR-16 source permute; one
// barrier per 64-col tile. ~190 VGPR, no spill at (256,2).
__global__ __launch_bounds__(256, 2) void k_sim(const ushort* __restrict__ xb,
                                                const unsigned char* __restrict__ lab8,
                                                float2* __restrict__ ppart,
                                                int N, int jpb) {
  __shared__ ushort ldsB[2][64 * 128];  // 2 x 16 KB
  const int tid = threadIdx.x;
  const int lane = tid & 63;
  const int wv = tid >> 6;
  const int l31 = lane & 31, g2 = lane >> 5;
  const int l15 = lane & 15, g4 = lane >> 4;
  const int i0 = blockIdx.y * 256;  // 256-row strip
  const int c = blockIdx.x;
  const int jt0 = c * jpb;

  // ---- stage first B tile (64 rows x 128 cols bf16 = 16 KB) ----
  {
    const int j0 = jt0 * 64;
#pragma unroll
    for (int it = 0; it < 4; ++it) {
      const int r0 = it * 16 + wv * 4;  // wave-uniform LDS row base
      const int lr = r0 + g4;
      const int kb = l15 ^ (lr & 15);
      const ushort* gp = xb + (size_t)(j0 + lr) * 128 + kb * 8;
      __builtin_amdgcn_global_load_lds((GAS void*)gp, (LAS void*)&ldsB[0][r0 * 128], 16, 0, 0);
    }
  }

  // ---- A fragments from global (L2-hot): rows i0 + wv*64 + rh*32 + l31 ----
  bf16x8 af[2][8];
#pragma unroll
  for (int rh = 0; rh < 2; ++rh) {
    const ushort* ap = xb + (size_t)(i0 + wv * 64 + rh * 32 + l31) * 128 + g2 * 8;
#pragma unroll
    for (int kt = 0; kt < 8; ++kt) af[rh][kt] = *(const bf16x8*)(ap + kt * 16);
  }

  // row labels byte-packed (C=64 < 256): liw[rh][q] holds rows
  // wv*64 + rh*32 + 8q + 4*g2 + {0..3}  (C/D row = (r&3)+8*(r>>2)+4*g2)
  const uint* lab32 = (const uint*)lab8;
  uint liw[2][4];
#pragma unroll
  for (int rh = 0; rh < 2; ++rh)
#pragma unroll
    for (int q = 0; q < 4; ++q)
      liw[rh][q] = lab32[(i0 + wv * 64 + rh * 32 + 8 * q + 4 * g2) >> 2];

  floatx16 vneg[2], vpos[2];
#pragma unroll
  for (int rh = 0; rh < 2; ++rh) {
    vneg[rh] = (floatx16)(0.0f);
    vpos[rh] = (floatx16)(0.0f);
  }
  __syncthreads();  // B0 staged (vmcnt drained per wave at barrier)

  for (int t = 0; t < jpb; ++t) {
    const int j0 = (jt0 + t) * 64;
    const int buf = t & 1;
    if (t + 1 < jpb) {  // prefetch next B into other buffer; lands during compute
      const int jn = j0 + 64;
#pragma unroll
      for (int it = 0; it < 4; ++it) {
        const int r0 = it * 16 + wv * 4;
        const int lr = r0 + g4;
        const int kb = l15 ^ (lr & 15);
        const ushort* gp = xb + (size_t)(jn + lr) * 128 + kb * 8;
        __builtin_amdgcn_global_load_lds((GAS void*)gp, (LAS void*)&ldsB[buf ^ 1][r0 * 128], 16, 0, 0);
      }
    }
    const int dlt = j0 - i0;            // tile touches diagonal iff dlt in [0,256)
    const bool diag = ((unsigned)dlt < 256u);

    // per col-half: 8 ds_read_b128 feed 16 MFMAs (2 row-halves), then epilogue
#pragma unroll
    for (int ch = 0; ch < 2; ++ch) {
      const int lj = lab8[j0 + ch * 32 + l31];  // column label (per lane)
      const int brow = ch * 32 + l31;
      const int bswz = brow & 15;
      floatx16 acc0 = (floatx16)(0.0f), acc1 = (floatx16)(0.0f);
      __builtin_amdgcn_s_setprio(1);
#pragma unroll
      for (int kt = 0; kt < 8; ++kt) {
        const bf16x8 b = *(const bf16x8*)&ldsB[buf][brow * 128 + (((kt * 2 + g2) ^ bswz) * 8)];
        acc0 = __builtin_amdgcn_mfma_f32_32x32x16_bf16(af[0][kt], b, acc0, 0, 0, 0);
        acc1 = __builtin_amdgcn_mfma_f32_32x32x16_bf16(af[1][kt], b, acc1, 0, 0, 0);
      }
      __builtin_amdgcn_s_setprio(0);

      const int jc = dlt + ch * 32 + l31;  // strip-relative diag col
      auto epi = [&](bool DG) {
#pragma unroll
        for (int rh = 0; rh < 2; ++rh) {
#pragma unroll
          for (int r = 0; r < 16; ++r) {
            const int lr = (liw[rh][r >> 2] >> ((r & 3) * 8)) & 255;
            float e = EXP2F(rh ? acc1[r] : acc0[r]);
            if (DG) {
              const int ir = wv * 64 + rh * 32 + (r & 3) + 8 * (r >> 2) + 4 * g2;
              if (ir == jc) e = 0.0f;  // exclude self-similarity exactly
            }
            vneg[rh][r] += e;
            vpos[rh][r] += (lr == lj) ? e : 0.0f;
          }
        }
      };
      if (diag) epi(true); else epi(false);
    }
    __syncthreads();  // all reads of buf done; prefetch(t+1) already drained
  }

  // ---- flush: reduce over 32 col-lanes; single writer lane per row ----
#pragma unroll
  for (int rh = 0; rh < 2; ++rh) {
#pragma unroll
    for (int r = 0; r < 16; ++r) {
      float n = vneg[rh][r], p = vpos[rh][r];
#pragma unroll
      for (int m = 1; m < 32; m <<= 1) {
        n += __shfl_xor(n, m, 64);
        p += __shfl_xor(p, m, 64);
      }
      if (l31 == 0) {
        const int row = i0 + wv * 64 + rh * 32 + (r & 3) + 8 * (r >> 2) + 4 * g2;
        ppart[(size_t)c * N + row] = float2{n, p};
      }
    }
  }
}

// ---------------- finalize: 32 blocks, 1 row/thread, atomic output ----------
__global__ __launch_bounds__(256) void k_final(const float2* __restrict__ ppart,
                                               const unsigned char* __restrict__ lab8,
                                               float* __restrict__ out,
                                               int N, int nplanes) {
  __shared__ int h[64];
  __shared__ double wsum[4];
  const int tid = threadIdx.x;
  if (tid < 64) h[tid] = 0;
  __syncthreads();
  for (int i = tid; i < N; i += 256) atomicAdd(&h[lab8[i] & 63], 1);
  __syncthreads();
  const int r = blockIdx.x * 256 + tid;
  double v = 0.0;
  if (r < N) {
    float n = 0.0f, p = 0.0f;
#pragma unroll 8
    for (int cc = 0; cc < nplanes; ++cc) {
      const float2 w = ppart[(size_t)cc * N + r];
      n += w.x;
      p += w.y;
    }
    const float cnt = (float)(h[lab8[r] & 63] - 1);
    v = (double)logf(n * cnt / p);
  }
#pragma unroll
  for (int m = 1; m < 64; m <<= 1) v += __shfl_xor(v, m, 64);
  if ((tid & 63) == 0) wsum[tid >> 6] = v;
  __syncthreads();
  // out is memset to 0 by the harness before launch; 32 block-adds of ~0.28
  // each -> atomic order rounding noise ~1e-6, far under threshold.
  if (tid == 0)
    atomicAdd(out, (float)((wsum[0] + wsum[1] + wsum[2] + wsum[3]) / (double)N));
}

extern "C" void kernel_launch(void* const* d_in, const int* in_sizes, int n_in,
                              void* d_out, int out_size, void* d_ws, size_t ws_size,
                              hipStream_t stream) {
  const float* x = (const float*)d_in[0];
  const int* raw_label = (const int*)d_in[1];
  const int N = in_sizes[1];  // 8192
  char* ws = (char*)d_ws;
  ushort* xb = (ushort*)ws;                             // N*128 bf16 = 2 MB
  float2* ppart = (float2*)(ws + (size_t)N * 128 * 2);  // JCH*N float2 = 1 MB
  unsigned char* lab8 = (unsigned char*)(ppart + (size_t)JCH * N);  // N bytes
  float* out = (float*)d_out;

  const int jpb = (N / 64) / JCH;   // 8 j-tiles per block
  const int nfb = (N + 255) / 256;  // 32 finalize blocks

  k_prep<<<dim3(N / 4), dim3(256), 0, stream>>>(x, raw_label, xb, lab8, N);
  k_sim<<<dim3(JCH, N / 256), dim3(256), 0, stream>>>(xb, lab8, ppart, N, jpb);
  k_final<<<dim3(nfb), dim3(256), 0, stream>>>(ppart, lab8, out, N, JCH);
}